// Round 1
// baseline (357.940 us; speedup 1.0000x reference)
//
#include <hip/hip_runtime.h>
#include <cstdint>
#include <cstddef>

#define LALPHA 0.2f
#define NEG_INF -9000000000000000.0f

constexpr int B = 4, S = 8, N = 1024, FIN = 128, FO = 64;
constexpr int BS = B * S;                 // 32
constexpr size_t H_ELEMS  = (size_t)BS * N * FO;   // 2,097,152
constexpr size_t F_ELEMS  = (size_t)BS * N;        // 32,768
constexpr size_t M_ELEMS  = (size_t)B * N * N;     // 4,194,304
constexpr size_t ADJ_ELEMS = (size_t)BS * N * N;   // 33,554,432

// ---------------- Kernel 1: h = x @ W, f1 = h@a1, f2 = h@a2 ----------------
__global__ __launch_bounds__(256) void k_h(
    const float* __restrict__ x, const float* __restrict__ W,
    const float* __restrict__ a, float* __restrict__ h,
    float* __restrict__ f1, float* __restrict__ f2)
{
    __shared__ float sW[FIN * FO];     // 32 KB
    __shared__ float sx[4][FIN];       // 2 KB
    const int t = threadIdx.x;
    for (int i = t; i < FIN * FO; i += 256) sW[i] = W[i];
    const size_t node0 = (size_t)blockIdx.x * 4;
    for (int i = t; i < 4 * FIN; i += 256) sx[i >> 7][i & 127] = x[node0 * FIN + i];
    __syncthreads();

    const int wave = t >> 6;           // 0..3 -> which node
    const int lane = t & 63;           // output feature o
    const size_t node = node0 + wave;

    float acc = 0.f;
    #pragma unroll
    for (int f = 0; f < FIN; ++f)
        acc = fmaf(sx[wave][f], sW[f * FO + lane], acc);

    h[node * FO + lane] = acc;

    float v1 = acc * a[lane];
    float v2 = acc * a[FO + lane];
    #pragma unroll
    for (int off = 32; off > 0; off >>= 1) {
        v1 += __shfl_xor(v1, off);
        v2 += __shfl_xor(v2, off);
    }
    if (lane == 0) { f1[node] = v1; f2[node] = v2; }
}

// ------- Kernel 2: softmax stats over s (axis=1) + Adj->float copy ---------
__global__ __launch_bounds__(256) void k_soft(
    const int* __restrict__ Adj, const float* __restrict__ f1,
    const float* __restrict__ f2, float* __restrict__ m_out,
    float* __restrict__ den_out, float* __restrict__ adjf)
{
    const size_t idx = (size_t)blockIdx.x * 256 + threadIdx.x; // b*N*N + i*N + j
    const int j = (int)(idx & (size_t)(N - 1));
    const int i = (int)((idx >> 10) & (size_t)(N - 1));
    const int b = (int)(idx >> 20);

    float vals[S];
    float mx = NEG_INF;
    #pragma unroll
    for (int s = 0; s < S; ++s) {
        const int bs = b * S + s;
        const size_t off = ((size_t)bs << 20) + ((size_t)i << 10) + (size_t)j;
        const int ad = Adj[off];
        adjf[off] = (float)ad;
        float e = NEG_INF;
        if (ad > 0) {
            const float v = f1[(size_t)bs * N + i] + f2[(size_t)bs * N + j];
            e = v >= 0.f ? v : LALPHA * v;
        }
        vals[s] = e;
        mx = fmaxf(mx, e);
    }
    float sum = 0.f;
    #pragma unroll
    for (int s = 0; s < S; ++s) sum += __expf(vals[s] - mx);
    m_out[idx] = mx;
    den_out[idx] = sum;
}

// ---------- Kernel 3: h_prime = att @ h (recompute att), then elu ----------
__global__ __launch_bounds__(256) void k_av(
    const int* __restrict__ Adj, const float* __restrict__ f1,
    const float* __restrict__ f2, const float* __restrict__ m_in,
    const float* __restrict__ den_in, const float* __restrict__ h,
    float* __restrict__ out)
{
    const int bs    = blockIdx.x >> 5;   // 0..31
    const int itile = blockIdx.x & 31;   // 0..31
    const int b     = bs >> 3;

    __shared__ float sh[128][64];        // 32 KB  h tile (j-local, o)
    __shared__ float sa[32][128];        // 16 KB  att tile (i-local, j-local)

    const int t  = threadIdx.x;
    const int o  = t & 63;
    const int ib = t >> 6;               // 0..3 row group
    const int i0 = itile * 32;

    float acc[8] = {0.f,0.f,0.f,0.f,0.f,0.f,0.f,0.f};
    const float* hbase = h + ((size_t)bs << 16);   // bs*1024*64

    for (int jt = 0; jt < 8; ++jt) {
        const int j0 = jt * 128;

        // stage h tile: 128 rows x 64 cols, as float4
        for (int k = t; k < 2048; k += 256) {
            const int jj = k >> 4, c = k & 15;
            const float4 v = *(const float4*)(hbase + ((size_t)(j0 + jj) << 6) + c * 4);
            *(float4*)&sh[jj][c * 4] = v;
        }
        // stage att tile: recompute att[b,s,i,j] = exp(e - m)/den
        for (int k = t; k < 4096; k += 256) {
            const int ii = k >> 7, jj = k & 127;
            const int gi = i0 + ii, gj = j0 + jj;
            const size_t aoff = ((size_t)bs << 20) + ((size_t)gi << 10) + (size_t)gj;
            const size_t moff = ((size_t)b  << 20) + ((size_t)gi << 10) + (size_t)gj;
            const int ad = Adj[aoff];
            float e = NEG_INF;
            if (ad > 0) {
                const float v = f1[(size_t)bs * N + gi] + f2[(size_t)bs * N + gj];
                e = v >= 0.f ? v : LALPHA * v;
            }
            sa[ii][jj] = __expf(e - m_in[moff]) / den_in[moff];
        }
        __syncthreads();

        #pragma unroll 2
        for (int jj4 = 0; jj4 < 128; jj4 += 4) {
            float4 av[8];
            #pragma unroll
            for (int r = 0; r < 8; ++r)
                av[r] = *(const float4*)&sa[ib * 8 + r][jj4];
            #pragma unroll
            for (int q = 0; q < 4; ++q) {
                const float hv = sh[jj4 + q][o];
                #pragma unroll
                for (int r = 0; r < 8; ++r)
                    acc[r] = fmaf(((const float*)&av[r])[q], hv, acc[r]);
            }
        }
        __syncthreads();
    }

    #pragma unroll
    for (int r = 0; r < 8; ++r) {
        const float xv = acc[r];
        const float ev = xv > 0.f ? xv : expm1f(xv);
        out[((size_t)bs * N + (size_t)(i0 + ib * 8 + r)) * FO + o] = ev;
    }
}

extern "C" void kernel_launch(void* const* d_in, const int* in_sizes, int n_in,
                              void* d_out, int out_size, void* d_ws, size_t ws_size,
                              hipStream_t stream)
{
    const float* x   = (const float*)d_in[0];
    const int*   Adj = (const int*)d_in[1];
    const float* W   = (const float*)d_in[2];
    const float* a   = (const float*)d_in[3];

    float* out = (float*)d_out;
    float* ws  = (float*)d_ws;

    float* h   = ws;                          // 2,097,152
    float* f1  = h  + H_ELEMS;                // 32,768
    float* f2  = f1 + F_ELEMS;                // 32,768
    float* m   = f2 + F_ELEMS;                // 4,194,304
    float* den = m  + M_ELEMS;                // 4,194,304

    float* out_h   = out;                     // elu(h_prime): 2,097,152
    float* out_adj = out + H_ELEMS;           // Adj as float: 33,554,432

    hipLaunchKernelGGL(k_h,    dim3((BS * N) / 4), dim3(256), 0, stream, x, W, a, h, f1, f2);
    hipLaunchKernelGGL(k_soft, dim3((int)(M_ELEMS / 256)), dim3(256), 0, stream, Adj, f1, f2, m, den, out_adj);
    hipLaunchKernelGGL(k_av,   dim3(BS * 32), dim3(256), 0, stream, Adj, f1, f2, m, den, h, out_h);
}

// Round 2
// 219.483 us; speedup vs baseline: 1.6308x; 1.6308x over previous
//
#include <hip/hip_runtime.h>
#include <cstdint>
#include <cstddef>

#define LALPHA 0.2f
#define NEG_INF -9000000000000000.0f

constexpr int N_ = 1024;
constexpr int FIN = 128, FO = 64;
constexpr int BS = 32;
constexpr size_t H_ELEMS = (size_t)BS * N_ * FO;   // 2,097,152
constexpr size_t F_ELEMS = (size_t)BS * N_;        // 32,768

typedef __attribute__((ext_vector_type(8))) short short8;
typedef __attribute__((ext_vector_type(4))) float floatx4;

static __device__ __forceinline__ unsigned short f2bf(float x) {
    union { float f; unsigned u; } v; v.f = x;
    unsigned r = v.u + 0x7FFF + ((v.u >> 16) & 1);
    return (unsigned short)(r >> 16);
}

// ---------------- Kernel 1: h = x @ W, f1 = h@a1, f2 = h@a2 ----------------
__global__ __launch_bounds__(256) void k_h(
    const float* __restrict__ x, const float* __restrict__ W,
    const float* __restrict__ a, float* __restrict__ h,
    float* __restrict__ f1, float* __restrict__ f2)
{
    __shared__ float sW[FIN * FO];     // 32 KB
    __shared__ float sx[4][FIN];       // 2 KB
    const int t = threadIdx.x;
    for (int i = t; i < FIN * FO; i += 256) sW[i] = W[i];
    const size_t node0 = (size_t)blockIdx.x * 4;
    for (int i = t; i < 4 * FIN; i += 256) sx[i >> 7][i & 127] = x[node0 * FIN + i];
    __syncthreads();

    const int wave = t >> 6;
    const int lane = t & 63;
    const size_t node = node0 + wave;

    float acc = 0.f;
    #pragma unroll
    for (int f = 0; f < FIN; ++f)
        acc = fmaf(sx[wave][f], sW[f * FO + lane], acc);

    h[node * FO + lane] = acc;

    float v1 = acc * a[lane];
    float v2 = acc * a[FO + lane];
    #pragma unroll
    for (int off = 32; off > 0; off >>= 1) {
        v1 += __shfl_xor(v1, off);
        v2 += __shfl_xor(v2, off);
    }
    if (lane == 0) { f1[node] = v1; f2[node] = v2; }
}

// ------------- Kernel 2: transpose+convert h -> hT bf16 [bs][o][j] ----------
__global__ __launch_bounds__(256) void k_tr(
    const float* __restrict__ h, unsigned short* __restrict__ hT)
{
    __shared__ float lt[64][65];
    const int bs = blockIdx.x >> 4;
    const int n0 = (blockIdx.x & 15) * 64;
    const int t = threadIdx.x;
    const float* hb = h + ((size_t)bs << 16) + ((size_t)n0 << 6);
    #pragma unroll
    for (int k = 0; k < 4; ++k) {
        const int r = (t >> 4) + k * 16;
        const int c = (t & 15) * 4;
        const float4 v = *(const float4*)(hb + ((size_t)r << 6) + c);
        lt[r][c] = v.x; lt[r][c + 1] = v.y; lt[r][c + 2] = v.z; lt[r][c + 3] = v.w;
    }
    __syncthreads();
    const int o = t >> 2, ch = (t & 3) * 16;
    unsigned short tmp[16];
    #pragma unroll
    for (int q = 0; q < 16; ++q) tmp[q] = f2bf(lt[ch + q][o]);
    unsigned short* dst = hT + ((size_t)bs << 16) + ((size_t)o << 10) + n0 + ch;
    *(uint4*)dst = *(uint4*)tmp;
    *(uint4*)(dst + 8) = *(uint4*)(tmp + 8);
}

// ---- Kernel 3: fused softmax-over-s + adjf copy + MFMA att@h + elu --------
// block: (b, 16-row i-tile), 256 threads (4 waves). Wave w owns s = {2w, 2w+1}.
__global__ __launch_bounds__(256) void k_av(
    const int* __restrict__ Adj, const float* __restrict__ f1,
    const float* __restrict__ f2, const unsigned short* __restrict__ hT,
    float* __restrict__ out_h, float* __restrict__ out_adj)
{
    // att[s][ii][jj] bf16, jj stored in 8 chunks of 8, chunk XOR-swizzled by (ii&7)
    __shared__ __align__(16) unsigned short att[8][16][64];   // 16 KB

    const int b  = blockIdx.x >> 6;
    const int i0 = (blockIdx.x & 63) * 16;
    const int t  = threadIdx.x;

    // phase-1 mapping: thread -> (ii, 4 consecutive jj)
    const int p_jj = (t & 15) * 4;
    const int p_ii = t >> 4;
    const int gi   = i0 + p_ii;

    // phase-2 mapping
    const int w  = t >> 6;
    const int l  = t & 63;
    const int fr = l & 15;    // fragment row (A) / col (B,D)
    const int fg = l >> 4;    // k-group

    float fi[8];
    #pragma unroll
    for (int s = 0; s < 8; ++s) fi[s] = f1[(size_t)(b * 8 + s) * N_ + gi];

    floatx4 acc[2][4];
    #pragma unroll
    for (int si = 0; si < 2; ++si)
        #pragma unroll
        for (int n = 0; n < 4; ++n)
            acc[si][n] = (floatx4){0.f, 0.f, 0.f, 0.f};

    for (int jt = 0; jt < 16; ++jt) {
        const int j0 = jt * 64;

        // ---------------- phase 1: softmax over s + adjf ----------------
        float ev[8][4];
        #pragma unroll
        for (int s = 0; s < 8; ++s) {
            const size_t aoff = ((size_t)(b * 8 + s) << 20) + ((size_t)gi << 10) + (size_t)(j0 + p_jj);
            const int4 ad = *(const int4*)(Adj + aoff);
            *(float4*)(out_adj + aoff) =
                make_float4((float)ad.x, (float)ad.y, (float)ad.z, (float)ad.w);
            const float4 fj = *(const float4*)(f2 + (size_t)(b * 8 + s) * N_ + j0 + p_jj);
            const float v0 = fi[s] + fj.x, v1 = fi[s] + fj.y;
            const float v2 = fi[s] + fj.z, v3 = fi[s] + fj.w;
            ev[s][0] = ad.x > 0 ? (v0 >= 0.f ? v0 : LALPHA * v0) : NEG_INF;
            ev[s][1] = ad.y > 0 ? (v1 >= 0.f ? v1 : LALPHA * v1) : NEG_INF;
            ev[s][2] = ad.z > 0 ? (v2 >= 0.f ? v2 : LALPHA * v2) : NEG_INF;
            ev[s][3] = ad.w > 0 ? (v3 >= 0.f ? v3 : LALPHA * v3) : NEG_INF;
        }
        #pragma unroll
        for (int q = 0; q < 4; ++q) {
            float m = NEG_INF;
            #pragma unroll
            for (int s = 0; s < 8; ++s) m = fmaxf(m, ev[s][q]);
            float p[8], den = 0.f;
            #pragma unroll
            for (int s = 0; s < 8; ++s) { p[s] = __expf(ev[s][q] - m); den += p[s]; }
            const float r = 1.0f / den;
            #pragma unroll
            for (int s = 0; s < 8; ++s) ev[s][q] = p[s] * r;
        }
        {
            const int chs  = (p_jj >> 3) ^ (p_ii & 7);
            const int boff = chs * 16 + (p_jj & 7) * 2;
            #pragma unroll
            for (int s = 0; s < 8; ++s) {
                ushort4 wv;
                wv.x = f2bf(ev[s][0]); wv.y = f2bf(ev[s][1]);
                wv.z = f2bf(ev[s][2]); wv.w = f2bf(ev[s][3]);
                *(ushort4*)((char*)&att[s][p_ii][0] + boff) = wv;
            }
        }
        __syncthreads();

        // ---------------- phase 2: MFMA ----------------
        #pragma unroll
        for (int ks = 0; ks < 2; ++ks) {
            short8 af[2];
            #pragma unroll
            for (int si = 0; si < 2; ++si) {
                const int s = 2 * w + si;
                const int c = (ks * 4 + fg) ^ (fr & 7);
                af[si] = *(const short8*)((const char*)&att[s][fr][0] + c * 16);
            }
            #pragma unroll
            for (int n = 0; n < 4; ++n) {
                #pragma unroll
                for (int si = 0; si < 2; ++si) {
                    const int bs = b * 8 + 2 * w + si;
                    const short8 bf = *(const short8*)(
                        hT + ((size_t)bs << 16) + (size_t)(n * 16 + fr) * N_ + j0 + ks * 32 + fg * 8);
                    acc[si][n] = __builtin_amdgcn_mfma_f32_16x16x32_bf16(af[si], bf, acc[si][n], 0, 0, 0);
                }
            }
        }
        __syncthreads();
    }

    // ---------------- epilogue: elu + store ----------------
    #pragma unroll
    for (int si = 0; si < 2; ++si) {
        const int bs = b * 8 + 2 * w + si;
        #pragma unroll
        for (int n = 0; n < 4; ++n) {
            #pragma unroll
            for (int r = 0; r < 4; ++r) {
                const float xv = acc[si][n][r];
                const float evv = xv > 0.f ? xv : expm1f(xv);
                out_h[((size_t)bs << 16) + (size_t)(i0 + fg * 4 + r) * FO + n * 16 + fr] = evv;
            }
        }
    }
}

extern "C" void kernel_launch(void* const* d_in, const int* in_sizes, int n_in,
                              void* d_out, int out_size, void* d_ws, size_t ws_size,
                              hipStream_t stream)
{
    const float* x   = (const float*)d_in[0];
    const int*   Adj = (const int*)d_in[1];
    const float* W   = (const float*)d_in[2];
    const float* a   = (const float*)d_in[3];

    float* out = (float*)d_out;
    float* ws  = (float*)d_ws;

    float* h  = ws;                                // 2,097,152 f32
    float* f1 = h + H_ELEMS;                       // 32,768
    float* f2 = f1 + F_ELEMS;                      // 32,768
    unsigned short* hT = (unsigned short*)(f2 + F_ELEMS);  // 2,097,152 bf16

    float* out_h   = out;                          // elu(h_prime)
    float* out_adj = out + H_ELEMS;                // Adj as float

    hipLaunchKernelGGL(k_h,  dim3(BS * N_ / 4), dim3(256), 0, stream, x, W, a, h, f1, f2);
    hipLaunchKernelGGL(k_tr, dim3(BS * 16),     dim3(256), 0, stream, h, hT);
    hipLaunchKernelGGL(k_av, dim3(4 * 64),      dim3(256), 0, stream, Adj, f1, f2, hT, out_h, out_adj);
}

// Round 3
// 143.529 us; speedup vs baseline: 2.4938x; 1.5292x over previous
//
#include <hip/hip_runtime.h>
#include <cstdint>
#include <cstddef>

#define LALPHA 0.2f
#define NEG_INF -9000000000000000.0f

constexpr int N_ = 1024;
constexpr int FIN = 128, FO = 64;
constexpr int BS = 32;
constexpr size_t H_ELEMS = (size_t)BS * N_ * FO;   // 2,097,152
constexpr size_t F_ELEMS = (size_t)BS * N_;        // 32,768
constexpr int SPLITK = 4;                          // j-range chunks

typedef __attribute__((ext_vector_type(8))) short short8;
typedef __attribute__((ext_vector_type(4))) float floatx4;

static __device__ __forceinline__ unsigned short f2bf(float x) {
    union { float f; unsigned u; } v; v.f = x;
    unsigned r = v.u + 0x7FFF + ((v.u >> 16) & 1);
    return (unsigned short)(r >> 16);
}

// ---------------- Kernel 1: h = x @ W, f1 = h@a1, f2 = h@a2 ----------------
__global__ __launch_bounds__(256) void k_h(
    const float* __restrict__ x, const float* __restrict__ W,
    const float* __restrict__ a, float* __restrict__ h,
    float* __restrict__ f1, float* __restrict__ f2)
{
    __shared__ float sW[FIN * FO];     // 32 KB
    __shared__ float sx[4][FIN];       // 2 KB
    const int t = threadIdx.x;
    for (int i = t; i < FIN * FO; i += 256) sW[i] = W[i];
    const size_t node0 = (size_t)blockIdx.x * 4;
    for (int i = t; i < 4 * FIN; i += 256) sx[i >> 7][i & 127] = x[node0 * FIN + i];
    __syncthreads();

    const int wave = t >> 6;
    const int lane = t & 63;
    const size_t node = node0 + wave;

    float acc = 0.f;
    #pragma unroll
    for (int f = 0; f < FIN; ++f)
        acc = fmaf(sx[wave][f], sW[f * FO + lane], acc);

    h[node * FO + lane] = acc;

    float v1 = acc * a[lane];
    float v2 = acc * a[FO + lane];
    #pragma unroll
    for (int off = 32; off > 0; off >>= 1) {
        v1 += __shfl_xor(v1, off);
        v2 += __shfl_xor(v2, off);
    }
    if (lane == 0) { f1[node] = v1; f2[node] = v2; }
}

// ------------- Kernel 2: transpose+convert h -> hT bf16 [bs][o][j] ----------
__global__ __launch_bounds__(256) void k_tr(
    const float* __restrict__ h, unsigned short* __restrict__ hT)
{
    __shared__ float lt[64][65];
    const int bs = blockIdx.x >> 4;
    const int n0 = (blockIdx.x & 15) * 64;
    const int t = threadIdx.x;
    const float* hb = h + ((size_t)bs << 16) + ((size_t)n0 << 6);
    #pragma unroll
    for (int k = 0; k < 4; ++k) {
        const int r = (t >> 4) + k * 16;
        const int c = (t & 15) * 4;
        const float4 v = *(const float4*)(hb + ((size_t)r << 6) + c);
        lt[r][c] = v.x; lt[r][c + 1] = v.y; lt[r][c + 2] = v.z; lt[r][c + 3] = v.w;
    }
    __syncthreads();
    const int o = t >> 2, ch = (t & 3) * 16;
    unsigned short tmp[16];
    #pragma unroll
    for (int q = 0; q < 16; ++q) tmp[q] = f2bf(lt[ch + q][o]);
    unsigned short* dst = hT + ((size_t)bs << 16) + ((size_t)o << 10) + n0 + ch;
    *(uint4*)dst = *(uint4*)tmp;
    *(uint4*)(dst + 8) = *(uint4*)(tmp + 8);
}

// ---- Kernel 3: fused softmax-over-s + adjf copy + MFMA att@h (split-K) ----
// block: (kk, b, 16-row i-tile); handles j range [kk*256, kk*256+256).
__global__ __launch_bounds__(256, 4) void k_av(
    const int* __restrict__ Adj, const float* __restrict__ f1,
    const float* __restrict__ f2, const unsigned short* __restrict__ hT,
    float* __restrict__ part, float* __restrict__ out_adj)
{
    __shared__ __align__(16) unsigned short att[8][16][64];   // 16 KB

    const int bid   = blockIdx.x;
    const int kk    = bid >> 8;
    const int b     = (bid >> 6) & 3;
    const int i0    = (bid & 63) * 16;
    const int t     = threadIdx.x;

    const int p_jj = (t & 15) * 4;
    const int p_ii = t >> 4;
    const int gi   = i0 + p_ii;

    const int w  = t >> 6;
    const int l  = t & 63;
    const int fr = l & 15;
    const int fg = l >> 4;

    float fi[8];
    #pragma unroll
    for (int s = 0; s < 8; ++s) fi[s] = f1[(size_t)(b * 8 + s) * N_ + gi];

    floatx4 acc[2][4];
    #pragma unroll
    for (int si = 0; si < 2; ++si)
        #pragma unroll
        for (int n = 0; n < 4; ++n)
            acc[si][n] = (floatx4){0.f, 0.f, 0.f, 0.f};

    for (int jt = 0; jt < 4; ++jt) {
        const int j0 = (kk * 4 + jt) * 64;

        // ---- phase 1: issue all Adj loads first (MLP), then softmax ----
        int4 ad[8];
        #pragma unroll
        for (int s = 0; s < 8; ++s) {
            const size_t aoff = ((size_t)(b * 8 + s) << 20) + ((size_t)gi << 10) + (size_t)(j0 + p_jj);
            ad[s] = *(const int4*)(Adj + aoff);
        }
        float ev[8][4];
        #pragma unroll
        for (int s = 0; s < 8; ++s) {
            const size_t aoff = ((size_t)(b * 8 + s) << 20) + ((size_t)gi << 10) + (size_t)(j0 + p_jj);
            *(float4*)(out_adj + aoff) =
                make_float4((float)ad[s].x, (float)ad[s].y, (float)ad[s].z, (float)ad[s].w);
            const float4 fj = *(const float4*)(f2 + (size_t)(b * 8 + s) * N_ + j0 + p_jj);
            const float v0 = fi[s] + fj.x, v1 = fi[s] + fj.y;
            const float v2 = fi[s] + fj.z, v3 = fi[s] + fj.w;
            ev[s][0] = ad[s].x > 0 ? (v0 >= 0.f ? v0 : LALPHA * v0) : NEG_INF;
            ev[s][1] = ad[s].y > 0 ? (v1 >= 0.f ? v1 : LALPHA * v1) : NEG_INF;
            ev[s][2] = ad[s].z > 0 ? (v2 >= 0.f ? v2 : LALPHA * v2) : NEG_INF;
            ev[s][3] = ad[s].w > 0 ? (v3 >= 0.f ? v3 : LALPHA * v3) : NEG_INF;
        }
        #pragma unroll
        for (int q = 0; q < 4; ++q) {
            float m = NEG_INF;
            #pragma unroll
            for (int s = 0; s < 8; ++s) m = fmaxf(m, ev[s][q]);
            float p[8], den = 0.f;
            #pragma unroll
            for (int s = 0; s < 8; ++s) { p[s] = __expf(ev[s][q] - m); den += p[s]; }
            const float r = 1.0f / den;
            #pragma unroll
            for (int s = 0; s < 8; ++s) ev[s][q] = p[s] * r;
        }
        {
            const int chs  = (p_jj >> 3) ^ (p_ii & 7);
            const int boff = chs * 16 + (p_jj & 7) * 2;
            #pragma unroll
            for (int s = 0; s < 8; ++s) {
                ushort4 wv;
                wv.x = f2bf(ev[s][0]); wv.y = f2bf(ev[s][1]);
                wv.z = f2bf(ev[s][2]); wv.w = f2bf(ev[s][3]);
                *(ushort4*)((char*)&att[s][p_ii][0] + boff) = wv;
            }
        }
        __syncthreads();

        // ---- phase 2: MFMA ----
        #pragma unroll
        for (int ks = 0; ks < 2; ++ks) {
            short8 af[2];
            #pragma unroll
            for (int si = 0; si < 2; ++si) {
                const int s = 2 * w + si;
                const int c = (ks * 4 + fg) ^ (fr & 7);
                af[si] = *(const short8*)((const char*)&att[s][fr][0] + c * 16);
            }
            #pragma unroll
            for (int n = 0; n < 4; ++n) {
                #pragma unroll
                for (int si = 0; si < 2; ++si) {
                    const int bs = b * 8 + 2 * w + si;
                    const short8 bf = *(const short8*)(
                        hT + ((size_t)bs << 16) + (size_t)(n * 16 + fr) * N_ + j0 + ks * 32 + fg * 8);
                    acc[si][n] = __builtin_amdgcn_mfma_f32_16x16x32_bf16(af[si], bf, acc[si][n], 0, 0, 0);
                }
            }
        }
        __syncthreads();
    }

    // ---- epilogue: write f32 partials (no elu) ----
    #pragma unroll
    for (int si = 0; si < 2; ++si) {
        const int bs = b * 8 + 2 * w + si;
        #pragma unroll
        for (int n = 0; n < 4; ++n) {
            #pragma unroll
            for (int r = 0; r < 4; ++r) {
                part[(size_t)kk * H_ELEMS + ((size_t)bs << 16)
                     + (size_t)(i0 + fg * 4 + r) * FO + n * 16 + fr] = acc[si][n][r];
            }
        }
    }
}

// ---------------- Kernel 4: combine split-K partials + elu ------------------
__global__ __launch_bounds__(256) void k_comb(
    const float* __restrict__ part, float* __restrict__ out_h)
{
    const size_t idx = ((size_t)blockIdx.x * 256 + threadIdx.x) * 4;
    float4 a0 = *(const float4*)(part + idx);
    const float4 a1 = *(const float4*)(part + H_ELEMS + idx);
    const float4 a2 = *(const float4*)(part + 2 * H_ELEMS + idx);
    const float4 a3 = *(const float4*)(part + 3 * H_ELEMS + idx);
    a0.x += a1.x + a2.x + a3.x;
    a0.y += a1.y + a2.y + a3.y;
    a0.z += a1.z + a2.z + a3.z;
    a0.w += a1.w + a2.w + a3.w;
    float4 r;
    r.x = a0.x > 0.f ? a0.x : expm1f(a0.x);
    r.y = a0.y > 0.f ? a0.y : expm1f(a0.y);
    r.z = a0.z > 0.f ? a0.z : expm1f(a0.z);
    r.w = a0.w > 0.f ? a0.w : expm1f(a0.w);
    *(float4*)(out_h + idx) = r;
}

extern "C" void kernel_launch(void* const* d_in, const int* in_sizes, int n_in,
                              void* d_out, int out_size, void* d_ws, size_t ws_size,
                              hipStream_t stream)
{
    const float* x   = (const float*)d_in[0];
    const int*   Adj = (const int*)d_in[1];
    const float* W   = (const float*)d_in[2];
    const float* a   = (const float*)d_in[3];

    float* out = (float*)d_out;
    float* ws  = (float*)d_ws;

    // ws layout (f32 slots): f1 | f2 | hT(bf16, H_ELEMS shorts) | h / partials
    float* f1 = ws;                                   // 32,768
    float* f2 = f1 + F_ELEMS;                         // 32,768
    unsigned short* hT = (unsigned short*)(f2 + F_ELEMS);   // H_ELEMS bf16
    float* h    = f2 + F_ELEMS + H_ELEMS / 2;         // 2M f32 (consumed by k_tr)
    float* part = h;                                  // 4 * H_ELEMS f32, aliases h

    float* out_h   = out;                             // elu(h_prime)
    float* out_adj = out + H_ELEMS;                   // Adj as float

    hipLaunchKernelGGL(k_h,    dim3(BS * N_ / 4),          dim3(256), 0, stream, x, W, a, h, f1, f2);
    hipLaunchKernelGGL(k_tr,   dim3(BS * 16),              dim3(256), 0, stream, h, hT);
    hipLaunchKernelGGL(k_av,   dim3(SPLITK * 4 * 64),      dim3(256), 0, stream, Adj, f1, f2, hT, part, out_adj);
    hipLaunchKernelGGL(k_comb, dim3((int)(H_ELEMS / 1024)), dim3(256), 0, stream, part, out_h);
}